// Round 8
// baseline (958.978 us; speedup 1.0000x reference)
//
#include <hip/hip_runtime.h>
#include <hip/hip_fp16.h>
#include <stdint.h>

#define D 256
#define BM 128
#define BN 128
#define EPS 68   // epilogue LDS row stride in floats

#define GLOBAL_AS __attribute__((address_space(1)))
#define LDS_AS    __attribute__((address_space(3)))

typedef _Float16 f16x8 __attribute__((ext_vector_type(8)));
typedef float f32x4 __attribute__((ext_vector_type(4)));

__device__ __forceinline__ void gload16(const unsigned short* g, unsigned short* l) {
    __builtin_amdgcn_global_load_lds((const GLOBAL_AS void*)g, (LDS_AS void*)l, 16, 0, 0);
}

// ---------------- prep: norms (f64 sum -> f32 store) + fp16 hi/scaled-lo split (PANEL-SLAB) ----------------
// slab layout: ushort off = ((panel*8 + chunk)*128 + row)*32 + rot_slot*8 + half*4
// rot_slot = (slot + (row>>1)) & 3  -> bank-conflict-free column reads in dist_mfma
__global__ void prep_kernel(const float* __restrict__ X, const float* __restrict__ E,
                            float* __restrict__ xn, float* __restrict__ en,
                            unsigned short* __restrict__ Xh, unsigned short* __restrict__ Xl,
                            unsigned short* __restrict__ Eh, unsigned short* __restrict__ El,
                            unsigned long long* __restrict__ keys,
                            unsigned int* __restrict__ hist,
                            unsigned long long* __restrict__ lossacc, int N, int K)
{
    int gid  = blockIdx.x * blockDim.x + threadIdx.x;
    int wid  = gid >> 6;
    int lane = threadIdx.x & 63;
    if (wid < N + K) {
        bool isX = wid < N;
        int r = isX ? wid : wid - N;
        const float* src = isX ? (X + (size_t)r * D) : (E + (size_t)r * D);
        float4 v = *(const float4*)(src + lane * 4);
        double s = (double)v.x*v.x + (double)v.y*v.y + (double)v.z*v.z + (double)v.w*v.w;
        #pragma unroll
        for (int o = 32; o >= 1; o >>= 1) s += __shfl_xor(s, o, 64);

        ushort4 h4, l4;
        {
            __half h;
            h = __float2half_rn(v.x); h4.x = __half_as_ushort(h);
            l4.x = __half_as_ushort(__float2half_rn((v.x - __half2float(h)) * 4096.0f));
            h = __float2half_rn(v.y); h4.y = __half_as_ushort(h);
            l4.y = __half_as_ushort(__float2half_rn((v.y - __half2float(h)) * 4096.0f));
            h = __float2half_rn(v.z); h4.z = __half_as_ushort(h);
            l4.z = __half_as_ushort(__float2half_rn((v.z - __half2float(h)) * 4096.0f));
            h = __float2half_rn(v.w); h4.w = __half_as_ushort(h);
            l4.w = __half_as_ushort(__float2half_rn((v.w - __half2float(h)) * 4096.0f));
        }
        int p = r >> 7, ri = r & 127;
        int c = lane >> 3, g = lane & 7;
        int slot = g >> 1, hf = g & 1;
        int slot_r = (slot + (ri >> 1)) & 3;
        size_t off = ((size_t)(p * 8 + c) * 128 + ri) * 32 + slot_r * 8 + hf * 4;
        if (isX) {
            *(ushort4*)(Xh + off) = h4; *(ushort4*)(Xl + off) = l4;
            if (lane == 0) xn[r] = (float)s;
        } else {
            *(ushort4*)(Eh + off) = h4; *(ushort4*)(El + off) = l4;
            if (lane == 0) en[r] = (float)s;
        }
    }
    int stride = gridDim.x * blockDim.x;
    for (int i = gid; i < N; i += stride) keys[i] = 0xFFFFFFFFFFFFFFFFull;
    for (int i = gid; i < K; i += stride) hist[i] = 0u;
    if (gid == 0) *lossacc = 0ull;
}

// ---------------- dist via fp16x2-split MFMA, gload_lds double-buffer, counted vmcnt ----------------
__global__ __launch_bounds__(256, 2) void dist_mfma(
    const unsigned short* __restrict__ Xh, const unsigned short* __restrict__ Xl,
    const unsigned short* __restrict__ Eh, const unsigned short* __restrict__ El,
    const float* __restrict__ xn, const float* __restrict__ en,
    float* __restrict__ dist, unsigned long long* __restrict__ keys,
    int N, int K)
{
    __shared__ alignas(16) unsigned short smem[2 * 4 * 4096];   // 64 KB

    const int tid  = threadIdx.x;
    const int lane = tid & 63;
    const int wv   = tid >> 6;
    const int wrow = (wv & 1) * 64;
    const int wcol = (wv >> 1) * 64;

    // XCD-aware swizzle (gridDim.x == 8)
    const int flat = blockIdx.y * gridDim.x + blockIdx.x;
    const int nf   = (flat & 7) * ((int)(gridDim.x * gridDim.y) >> 3) + (flat >> 3);
    const int bx   = nf & 7;
    const int by   = nf >> 3;
    const int row0 = by * BM;
    const int col0 = bx * BN;

    const unsigned short* gA_h = Xh + (size_t)by * 32768;
    const unsigned short* gA_l = Xl + (size_t)by * 32768;
    const unsigned short* gB_h = Eh + (size_t)bx * 32768;
    const unsigned short* gB_l = El + (size_t)bx * 32768;

    f32x4 acc[4][4];   // hh
    f32x4 acr[4][4];   // cross (scaled by 2^12)
    #pragma unroll
    for (int i = 0; i < 4; ++i)
        #pragma unroll
        for (int j = 0; j < 4; ++j) { acc[i][j] = {0.f,0.f,0.f,0.f}; acr[i][j] = {0.f,0.f,0.f,0.f}; }

    const int toff = tid * 8;

    #define STAGE(c_, b_)                                                           \
    {                                                                               \
        const int co = (c_) * 4096;                                                 \
        unsigned short* lb = smem + (b_) * 16384;                                   \
        _Pragma("unroll")                                                           \
        for (int t = 0; t < 2; ++t) {                                               \
            gload16(gA_h + co + t*2048 + toff, lb +         t*2048 + toff);         \
            gload16(gA_l + co + t*2048 + toff, lb +  4096 + t*2048 + toff);         \
            gload16(gB_h + co + t*2048 + toff, lb +  8192 + t*2048 + toff);         \
            gload16(gB_l + co + t*2048 + toff, lb + 12288 + t*2048 + toff);         \
        }                                                                           \
    }

    const int fr = lane & 15;
    const int kq = lane >> 4;
    const int q  = kq;

    // loop-invariant swizzled LDS offsets (ushort units)
    int offA[4], offB[4];
    #pragma unroll
    for (int i = 0; i < 4; ++i) {
        int rowA = wrow + i*16 + fr;
        offA[i] = rowA * 32 + ((kq + (rowA >> 1)) & 3) * 8;
        int rowB = wcol + i*16 + fr;
        offB[i] = rowB * 32 + ((kq + (rowB >> 1)) & 3) * 8;
    }

    STAGE(0, 0);
    asm volatile("s_waitcnt vmcnt(0)" ::: "memory");
    __builtin_amdgcn_s_barrier();
    __builtin_amdgcn_sched_barrier(0);

    for (int c = 0; c < 8; ++c) {
        const int b = c & 1;
        if (c < 7) {
            STAGE(c + 1, b ^ 1);
            asm volatile("s_waitcnt vmcnt(8)" ::: "memory");
        } else {
            asm volatile("s_waitcnt vmcnt(0)" ::: "memory");
        }
        __builtin_amdgcn_s_barrier();
        __builtin_amdgcn_sched_barrier(0);

        const unsigned short* buf = smem + b * 16384;
        f16x8 ah[4], bh[4], al[4], bl[4];
        #pragma unroll
        for (int i = 0; i < 4; ++i)
            ah[i] = *(const f16x8*)&buf[offA[i]];
        #pragma unroll
        for (int j = 0; j < 4; ++j)
            bh[j] = *(const f16x8*)&buf[8192 + offB[j]];
        __builtin_amdgcn_s_setprio(1);
        #pragma unroll
        for (int i = 0; i < 4; ++i)
            #pragma unroll
            for (int j = 0; j < 4; ++j)
                acc[i][j] = __builtin_amdgcn_mfma_f32_16x16x32_f16(ah[i], bh[j], acc[i][j], 0, 0, 0);
        #pragma unroll
        for (int j = 0; j < 4; ++j)
            bl[j] = *(const f16x8*)&buf[12288 + offB[j]];
        #pragma unroll
        for (int i = 0; i < 4; ++i)
            #pragma unroll
            for (int j = 0; j < 4; ++j)
                acr[i][j] = __builtin_amdgcn_mfma_f32_16x16x32_f16(ah[i], bl[j], acr[i][j], 0, 0, 0);
        #pragma unroll
        for (int i = 0; i < 4; ++i)
            al[i] = *(const f16x8*)&buf[4096 + offA[i]];
        #pragma unroll
        for (int i = 0; i < 4; ++i)
            #pragma unroll
            for (int j = 0; j < 4; ++j)
                acr[i][j] = __builtin_amdgcn_mfma_f32_16x16x32_f16(al[i], bh[j], acr[i][j], 0, 0, 0);
        __builtin_amdgcn_s_setprio(0);

        asm volatile("s_waitcnt lgkmcnt(0)" ::: "memory");
        __builtin_amdgcn_s_barrier();
        __builtin_amdgcn_sched_barrier(0);
    }

    // ---- epilogue, all f32 ----
    float ecv[4];
    #pragma unroll
    for (int j = 0; j < 4; ++j) ecv[j] = en[col0 + wcol + j*16 + fr];

    char* arena = (char*)smem + wv * 16384;

    // Phase A: per-thread keys -> LDS table -> per-lane row reduce -> atomicMin
    {
        unsigned long long* kbuf = (unsigned long long*)arena;   // [64][17] u64 = 8704B
        #pragma unroll
        for (int i = 0; i < 4; ++i) {
            #pragma unroll
            for (int r = 0; r < 4; ++r) {
                const int lr = i*16 + q*4 + r;
                unsigned long long bk = 0xFFFFFFFFFFFFFFFFull;
                #pragma unroll
                for (int j = 0; j < 4; ++j) {
                    float dotf = fmaf(acr[i][j][r], 0.000244140625f, acc[i][j][r]);
                    float m    = fmaf(-2.0f, dotf, ecv[j]);
                    uint32_t u = __float_as_uint(m);
                    u ^= ((uint32_t)((int32_t)u >> 31)) | 0x80000000u;
                    unsigned long long kk = ((unsigned long long)u << 32)
                                          | (unsigned)(col0 + wcol + j*16 + fr);
                    if (kk < bk) bk = kk;
                }
                kbuf[lr * 17 + fr] = bk;
            }
        }
        asm volatile("s_waitcnt lgkmcnt(0)" ::: "memory");
        unsigned long long best = 0xFFFFFFFFFFFFFFFFull;
        #pragma unroll
        for (int s = 0; s < 16; ++s) {
            unsigned long long v = kbuf[lane * 17 + s];
            if (v < best) best = v;
        }
        // rebase key to full distance dv = xn + m so keys carry d_min for the loss
        {
            uint32_t u = (uint32_t)(best >> 32);
            uint32_t fb = (u & 0x80000000u) ? (u ^ 0x80000000u) : ~u;
            float m = __uint_as_float(fb);
            float dv = xn[row0 + wrow + lane] + m;
            uint32_t du = __float_as_uint(dv);
            du ^= ((uint32_t)((int32_t)du >> 31)) | 0x80000000u;
            best = ((unsigned long long)du << 32) | (best & 0xFFFFFFFFull);
        }
        atomicMin(&keys[row0 + wrow + lane], best);
        asm volatile("s_waitcnt lgkmcnt(0)" ::: "memory");
    }

    // Phase B: dist values via LDS-staged full-line float4 stores
    {
        float xr32[4][4];
        #pragma unroll
        for (int i = 0; i < 4; ++i)
            #pragma unroll
            for (int r = 0; r < 4; ++r)
                xr32[i][r] = xn[row0 + wrow + i*16 + q*4 + r];

        float* ebuf = (float*)arena;
        #pragma unroll
        for (int h = 0; h < 2; ++h) {
            #pragma unroll
            for (int i2 = 0; i2 < 2; ++i2) {
                const int i = h * 2 + i2;
                #pragma unroll
                for (int r = 0; r < 4; ++r) {
                    #pragma unroll
                    for (int j = 0; j < 4; ++j) {
                        float dotf = fmaf(acr[i][j][r], 0.000244140625f, acc[i][j][r]);
                        float dv   = fmaf(-2.0f, dotf, xr32[i][r] + ecv[j]);
                        ebuf[(i2*16 + q*4 + r) * EPS + j*16 + fr] = dv;
                    }
                }
            }
            asm volatile("s_waitcnt lgkmcnt(0)" ::: "memory");
            #pragma unroll
            for (int s = 0; s < 8; ++s) {
                const int rl = s*4 + q;
                float4 v = *(const float4*)&ebuf[rl * EPS + fr * 4];
                const int grow = row0 + wrow + h*32 + rl;
                *(float4*)&dist[(size_t)grow * K + col0 + wcol + fr*4] = v;
            }
            asm volatile("s_waitcnt lgkmcnt(0)" ::: "memory");
        }
    }
    #undef STAGE
}

// ---------------- per-row outputs: gather quantized, one-hot, idx, hist, loss from key ----------------
__global__ void row_out(const float* __restrict__ E,
                        const unsigned long long* __restrict__ keys,
                        float* __restrict__ quant, float* __restrict__ enc,
                        float* __restrict__ idxf, unsigned int* __restrict__ hist,
                        unsigned long long* __restrict__ lossacc, int N, int K)
{
    int wid  = (blockIdx.x * blockDim.x + threadIdx.x) >> 6;
    int lane = threadIdx.x & 63;
    if (wid >= N) return;
    unsigned long long key = keys[wid];
    int idx = (int)(unsigned)(key & 0xFFFFFFFFull);

    float4 q4 = *(const float4*)(E + (size_t)idx * D + lane*4);
    *(float4*)(quant + (size_t)wid * D + lane*4) = q4;

    #pragma unroll
    for (int c = 0; c < 4; ++c) {
        int col = c * 256 + lane * 4;
        float4 v;
        v.x = (col + 0 == idx) ? 1.0f : 0.0f;
        v.y = (col + 1 == idx) ? 1.0f : 0.0f;
        v.z = (col + 2 == idx) ? 1.0f : 0.0f;
        v.w = (col + 3 == idx) ? 1.0f : 0.0f;
        *(float4*)(enc + (size_t)wid * K + col) = v;
    }
    if (lane == 0) {
        idxf[wid] = (float)idx;
        atomicAdd(&hist[idx], 1u);
        // decode d_min from the monotone key bits; accumulate fixed-point (deterministic)
        uint32_t u = (uint32_t)(key >> 32);
        uint32_t fb = (u & 0x80000000u) ? (u ^ 0x80000000u) : ~u;
        float dv = __uint_as_float(fb);
        long long fx = (long long)llrintf(dv * 1048576.0f);
        atomicAdd(lossacc, (unsigned long long)fx);
    }
}

// ---------------- finalize: vq_loss from fixed-point acc + perplexity from hist ----------------
__global__ void finalize_kernel(const unsigned long long* __restrict__ lossacc,
                                const unsigned int* __restrict__ hist,
                                float* __restrict__ out_loss,
                                float* __restrict__ out_perp,
                                int N, int K)
{
    int tid = threadIdx.x;
    float ent = 0.0f;
    if (tid < K) {
        float p = (float)hist[tid] / (float)N;
        ent = p * logf(p + 1e-10f);
    }
    #pragma unroll
    for (int o = 32; o >= 1; o >>= 1) ent += __shfl_xor(ent, o, 64);
    __shared__ float se[16];
    int w = tid >> 6, lane = tid & 63;
    if (lane == 0) se[w] = ent;
    __syncthreads();
    if (tid == 0) {
        float En = 0.0f;
        for (int i = 0; i < 16; ++i) En += se[i];
        long long fx = (long long)(*lossacc);
        double L = (double)fx / 1048576.0;
        *out_loss = (float)(0.25 * L / ((double)N * (double)D));
        *out_perp = expf(-En);
    }
}

extern "C" void kernel_launch(void* const* d_in, const int* in_sizes, int n_in,
                              void* d_out, int out_size, void* d_ws, size_t ws_size,
                              hipStream_t stream)
{
    const float* X = (const float*)d_in[0];
    const float* E = (const float*)d_in[1];
    const int N = in_sizes[0] / D;   // 65536
    const int K = in_sizes[1] / D;   // 1024
    float* out = (float*)d_out;

    const size_t O1 = 1;                          // quantized_st  [N*D]
    const size_t O2 = O1 + (size_t)N * D;         // perplexity    [1]
    const size_t O3 = O2 + 1;                     // encodings     [N*K]
    const size_t O4 = O3 + (size_t)N * K;         // distances     [N*K]
    const size_t O5 = O4 + (size_t)N * K;         // indices       [N]

    char* ws = (char*)d_ws;
    size_t off = 0;
    auto alloc = [&](size_t bytes) -> void* {
        void* p = ws + off;
        off += (bytes + 255) & ~(size_t)255;
        return p;
    };
    float* xn = (float*)alloc((size_t)N * 4);
    float* en = (float*)alloc((size_t)K * 4);
    unsigned long long* keys = (unsigned long long*)alloc((size_t)N * 8);
    unsigned int* hist = (unsigned int*)alloc((size_t)K * 4);
    unsigned long long* lossacc = (unsigned long long*)alloc(256);
    unsigned short* Xh = (unsigned short*)alloc((size_t)N * D * 2);
    unsigned short* Xl = (unsigned short*)alloc((size_t)N * D * 2);
    unsigned short* Eh = (unsigned short*)alloc((size_t)K * D * 2);
    unsigned short* El = (unsigned short*)alloc((size_t)K * D * 2);

    int prep_blocks = (N + K + 3) / 4;
    prep_kernel<<<prep_blocks, 256, 0, stream>>>(X, E, xn, en, Xh, Xl, Eh, El,
                                                 keys, hist, lossacc, N, K);

    dim3 g(K / BN, N / BM);
    dist_mfma<<<g, 256, 0, stream>>>(Xh, Xl, Eh, El, xn, en,
                                     out + O4, keys, N, K);

    row_out<<<N / 4, 256, 0, stream>>>(E, keys, out + O1, out + O3,
                                       out + O5, hist, lossacc, N, K);

    finalize_kernel<<<1, 1024, 0, stream>>>(lossacc, hist, out, out + O2, N, K);
}

// Round 9
// 235.529 us; speedup vs baseline: 4.0716x; 4.0716x over previous
//
#include <hip/hip_runtime.h>
#include <hip/hip_fp16.h>
#include <stdint.h>

#define D 256
#define BM 128
#define BN 128
#define EPS 68   // epilogue LDS row stride in floats

#define GLOBAL_AS __attribute__((address_space(1)))
#define LDS_AS    __attribute__((address_space(3)))

typedef _Float16 f16x8 __attribute__((ext_vector_type(8)));
typedef float f32x4 __attribute__((ext_vector_type(4)));

__device__ __forceinline__ void gload16(const unsigned short* g, unsigned short* l) {
    __builtin_amdgcn_global_load_lds((const GLOBAL_AS void*)g, (LDS_AS void*)l, 16, 0, 0);
}

// ---------------- prep: norms (f64 sum -> f32 store) + fp16 hi/scaled-lo split (PANEL-SLAB) ----------------
// slab layout: ushort off = ((panel*8 + chunk)*128 + row)*32 + rot_slot*8 + half*4
// rot_slot = (slot + (row>>1)) & 3  -> bank-conflict-free column reads in dist_mfma
__global__ void prep_kernel(const float* __restrict__ X, const float* __restrict__ E,
                            float* __restrict__ xn, float* __restrict__ en,
                            unsigned short* __restrict__ Xh, unsigned short* __restrict__ Xl,
                            unsigned short* __restrict__ Eh, unsigned short* __restrict__ El,
                            unsigned long long* __restrict__ keys,
                            unsigned int* __restrict__ hist, int N, int K)
{
    int gid  = blockIdx.x * blockDim.x + threadIdx.x;
    int wid  = gid >> 6;
    int lane = threadIdx.x & 63;
    if (wid < N + K) {
        bool isX = wid < N;
        int r = isX ? wid : wid - N;
        const float* src = isX ? (X + (size_t)r * D) : (E + (size_t)r * D);
        float4 v = *(const float4*)(src + lane * 4);
        double s = (double)v.x*v.x + (double)v.y*v.y + (double)v.z*v.z + (double)v.w*v.w;
        #pragma unroll
        for (int o = 32; o >= 1; o >>= 1) s += __shfl_xor(s, o, 64);

        ushort4 h4, l4;
        {
            __half h;
            h = __float2half_rn(v.x); h4.x = __half_as_ushort(h);
            l4.x = __half_as_ushort(__float2half_rn((v.x - __half2float(h)) * 4096.0f));
            h = __float2half_rn(v.y); h4.y = __half_as_ushort(h);
            l4.y = __half_as_ushort(__float2half_rn((v.y - __half2float(h)) * 4096.0f));
            h = __float2half_rn(v.z); h4.z = __half_as_ushort(h);
            l4.z = __half_as_ushort(__float2half_rn((v.z - __half2float(h)) * 4096.0f));
            h = __float2half_rn(v.w); h4.w = __half_as_ushort(h);
            l4.w = __half_as_ushort(__float2half_rn((v.w - __half2float(h)) * 4096.0f));
        }
        int p = r >> 7, ri = r & 127;
        int c = lane >> 3, g = lane & 7;
        int slot = g >> 1, hf = g & 1;
        int slot_r = (slot + (ri >> 1)) & 3;
        size_t off = ((size_t)(p * 8 + c) * 128 + ri) * 32 + slot_r * 8 + hf * 4;
        if (isX) {
            *(ushort4*)(Xh + off) = h4; *(ushort4*)(Xl + off) = l4;
            if (lane == 0) xn[r] = (float)s;
        } else {
            *(ushort4*)(Eh + off) = h4; *(ushort4*)(El + off) = l4;
            if (lane == 0) en[r] = (float)s;
        }
    }
    int stride = gridDim.x * blockDim.x;
    for (int i = gid; i < N; i += stride) keys[i] = 0xFFFFFFFFFFFFFFFFull;
    for (int i = gid; i < K; i += stride) hist[i] = 0u;
}

// ---------------- dist via fp16x2-split MFMA, gload_lds double-buffer, counted vmcnt ----------------
__global__ __launch_bounds__(256, 2) void dist_mfma(
    const unsigned short* __restrict__ Xh, const unsigned short* __restrict__ Xl,
    const unsigned short* __restrict__ Eh, const unsigned short* __restrict__ El,
    const float* __restrict__ xn, const float* __restrict__ en,
    float* __restrict__ dist, unsigned long long* __restrict__ keys,
    int N, int K)
{
    __shared__ alignas(16) unsigned short smem[2 * 4 * 4096];   // 64 KB

    const int tid  = threadIdx.x;
    const int lane = tid & 63;
    const int wv   = tid >> 6;
    const int wrow = (wv & 1) * 64;
    const int wcol = (wv >> 1) * 64;

    // XCD-aware swizzle (gridDim.x == 8)
    const int flat = blockIdx.y * gridDim.x + blockIdx.x;
    const int nf   = (flat & 7) * ((int)(gridDim.x * gridDim.y) >> 3) + (flat >> 3);
    const int bx   = nf & 7;
    const int by   = nf >> 3;
    const int row0 = by * BM;
    const int col0 = bx * BN;

    const unsigned short* gA_h = Xh + (size_t)by * 32768;
    const unsigned short* gA_l = Xl + (size_t)by * 32768;
    const unsigned short* gB_h = Eh + (size_t)bx * 32768;
    const unsigned short* gB_l = El + (size_t)bx * 32768;

    f32x4 acc[4][4];   // hh
    f32x4 acr[4][4];   // cross (scaled by 2^12)
    #pragma unroll
    for (int i = 0; i < 4; ++i)
        #pragma unroll
        for (int j = 0; j < 4; ++j) { acc[i][j] = {0.f,0.f,0.f,0.f}; acr[i][j] = {0.f,0.f,0.f,0.f}; }

    const int toff = tid * 8;

    #define STAGE(c_, b_)                                                           \
    {                                                                               \
        const int co = (c_) * 4096;                                                 \
        unsigned short* lb = smem + (b_) * 16384;                                   \
        _Pragma("unroll")                                                           \
        for (int t = 0; t < 2; ++t) {                                               \
            gload16(gA_h + co + t*2048 + toff, lb +         t*2048 + toff);         \
            gload16(gA_l + co + t*2048 + toff, lb +  4096 + t*2048 + toff);         \
            gload16(gB_h + co + t*2048 + toff, lb +  8192 + t*2048 + toff);         \
            gload16(gB_l + co + t*2048 + toff, lb + 12288 + t*2048 + toff);         \
        }                                                                           \
    }

    const int fr = lane & 15;
    const int kq = lane >> 4;
    const int q  = kq;

    // loop-invariant swizzled LDS offsets (ushort units)
    int offA[4], offB[4];
    #pragma unroll
    for (int i = 0; i < 4; ++i) {
        int rowA = wrow + i*16 + fr;
        offA[i] = rowA * 32 + ((kq + (rowA >> 1)) & 3) * 8;
        int rowB = wcol + i*16 + fr;
        offB[i] = rowB * 32 + ((kq + (rowB >> 1)) & 3) * 8;
    }

    STAGE(0, 0);
    asm volatile("s_waitcnt vmcnt(0)" ::: "memory");
    __builtin_amdgcn_s_barrier();
    __builtin_amdgcn_sched_barrier(0);

    for (int c = 0; c < 8; ++c) {
        const int b = c & 1;
        if (c < 7) {
            STAGE(c + 1, b ^ 1);
            asm volatile("s_waitcnt vmcnt(8)" ::: "memory");
        } else {
            asm volatile("s_waitcnt vmcnt(0)" ::: "memory");
        }
        __builtin_amdgcn_s_barrier();
        __builtin_amdgcn_sched_barrier(0);

        const unsigned short* buf = smem + b * 16384;
        f16x8 ah[4], bh[4], al[4], bl[4];
        #pragma unroll
        for (int i = 0; i < 4; ++i)
            ah[i] = *(const f16x8*)&buf[offA[i]];
        #pragma unroll
        for (int j = 0; j < 4; ++j)
            bh[j] = *(const f16x8*)&buf[8192 + offB[j]];
        __builtin_amdgcn_s_setprio(1);
        #pragma unroll
        for (int i = 0; i < 4; ++i)
            #pragma unroll
            for (int j = 0; j < 4; ++j)
                acc[i][j] = __builtin_amdgcn_mfma_f32_16x16x32_f16(ah[i], bh[j], acc[i][j], 0, 0, 0);
        #pragma unroll
        for (int j = 0; j < 4; ++j)
            bl[j] = *(const f16x8*)&buf[12288 + offB[j]];
        #pragma unroll
        for (int i = 0; i < 4; ++i)
            #pragma unroll
            for (int j = 0; j < 4; ++j)
                acr[i][j] = __builtin_amdgcn_mfma_f32_16x16x32_f16(ah[i], bl[j], acr[i][j], 0, 0, 0);
        #pragma unroll
        for (int i = 0; i < 4; ++i)
            al[i] = *(const f16x8*)&buf[4096 + offA[i]];
        #pragma unroll
        for (int i = 0; i < 4; ++i)
            #pragma unroll
            for (int j = 0; j < 4; ++j)
                acr[i][j] = __builtin_amdgcn_mfma_f32_16x16x32_f16(al[i], bh[j], acr[i][j], 0, 0, 0);
        __builtin_amdgcn_s_setprio(0);

        asm volatile("s_waitcnt lgkmcnt(0)" ::: "memory");
        __builtin_amdgcn_s_barrier();
        __builtin_amdgcn_sched_barrier(0);
    }

    // ---- epilogue, all f32 ----
    float ecv[4];
    #pragma unroll
    for (int j = 0; j < 4; ++j) ecv[j] = en[col0 + wcol + j*16 + fr];

    char* arena = (char*)smem + wv * 16384;

    // Phase A: per-thread keys -> LDS table -> per-lane row reduce -> atomicMin
    {
        unsigned long long* kbuf = (unsigned long long*)arena;   // [64][17] u64 = 8704B
        #pragma unroll
        for (int i = 0; i < 4; ++i) {
            #pragma unroll
            for (int r = 0; r < 4; ++r) {
                const int lr = i*16 + q*4 + r;
                unsigned long long bk = 0xFFFFFFFFFFFFFFFFull;
                #pragma unroll
                for (int j = 0; j < 4; ++j) {
                    float dotf = fmaf(acr[i][j][r], 0.000244140625f, acc[i][j][r]);
                    float m    = fmaf(-2.0f, dotf, ecv[j]);
                    uint32_t u = __float_as_uint(m);
                    u ^= ((uint32_t)((int32_t)u >> 31)) | 0x80000000u;
                    unsigned long long kk = ((unsigned long long)u << 32)
                                          | (unsigned)(col0 + wcol + j*16 + fr);
                    if (kk < bk) bk = kk;
                }
                kbuf[lr * 17 + fr] = bk;
            }
        }
        asm volatile("s_waitcnt lgkmcnt(0)" ::: "memory");
        unsigned long long best = 0xFFFFFFFFFFFFFFFFull;
        #pragma unroll
        for (int s = 0; s < 16; ++s) {
            unsigned long long v = kbuf[lane * 17 + s];
            if (v < best) best = v;
        }
        // rebase key to full distance dv = xn + m so keys carry d_min for the loss
        {
            uint32_t u = (uint32_t)(best >> 32);
            uint32_t fb = (u & 0x80000000u) ? (u ^ 0x80000000u) : ~u;
            float m = __uint_as_float(fb);
            float dv = xn[row0 + wrow + lane] + m;
            uint32_t du = __float_as_uint(dv);
            du ^= ((uint32_t)((int32_t)du >> 31)) | 0x80000000u;
            best = ((unsigned long long)du << 32) | (best & 0xFFFFFFFFull);
        }
        atomicMin(&keys[row0 + wrow + lane], best);
        asm volatile("s_waitcnt lgkmcnt(0)" ::: "memory");
    }

    // Phase B: dist values via LDS-staged full-line float4 stores
    {
        float xr32[4][4];
        #pragma unroll
        for (int i = 0; i < 4; ++i)
            #pragma unroll
            for (int r = 0; r < 4; ++r)
                xr32[i][r] = xn[row0 + wrow + i*16 + q*4 + r];

        float* ebuf = (float*)arena;
        #pragma unroll
        for (int h = 0; h < 2; ++h) {
            #pragma unroll
            for (int i2 = 0; i2 < 2; ++i2) {
                const int i = h * 2 + i2;
                #pragma unroll
                for (int r = 0; r < 4; ++r) {
                    #pragma unroll
                    for (int j = 0; j < 4; ++j) {
                        float dotf = fmaf(acr[i][j][r], 0.000244140625f, acc[i][j][r]);
                        float dv   = fmaf(-2.0f, dotf, xr32[i][r] + ecv[j]);
                        ebuf[(i2*16 + q*4 + r) * EPS + j*16 + fr] = dv;
                    }
                }
            }
            asm volatile("s_waitcnt lgkmcnt(0)" ::: "memory");
            #pragma unroll
            for (int s = 0; s < 8; ++s) {
                const int rl = s*4 + q;
                float4 v = *(const float4*)&ebuf[rl * EPS + fr * 4];
                const int grow = row0 + wrow + h*32 + rl;
                *(float4*)&dist[(size_t)grow * K + col0 + wcol + fr*4] = v;
            }
            asm volatile("s_waitcnt lgkmcnt(0)" ::: "memory");
        }
    }
    #undef STAGE
}

// ---------------- per-row outputs: gather quantized, one-hot, idx, hist, loss partial (no global atomics for loss) ----------------
__global__ void row_out(const float* __restrict__ E,
                        const unsigned long long* __restrict__ keys,
                        float* __restrict__ quant, float* __restrict__ enc,
                        float* __restrict__ idxf, unsigned int* __restrict__ hist,
                        float* __restrict__ partials, int N, int K)
{
    __shared__ float sdv[4];
    int wid  = (blockIdx.x * blockDim.x + threadIdx.x) >> 6;
    int wvb  = (threadIdx.x) >> 6;      // wave within block 0..3
    int lane = threadIdx.x & 63;
    unsigned long long key = keys[wid];
    int idx = (int)(unsigned)(key & 0xFFFFFFFFull);

    float4 q4 = *(const float4*)(E + (size_t)idx * D + lane*4);
    *(float4*)(quant + (size_t)wid * D + lane*4) = q4;

    #pragma unroll
    for (int c = 0; c < 4; ++c) {
        int col = c * 256 + lane * 4;
        float4 v;
        v.x = (col + 0 == idx) ? 1.0f : 0.0f;
        v.y = (col + 1 == idx) ? 1.0f : 0.0f;
        v.z = (col + 2 == idx) ? 1.0f : 0.0f;
        v.w = (col + 3 == idx) ? 1.0f : 0.0f;
        *(float4*)(enc + (size_t)wid * K + col) = v;
    }
    if (lane == 0) {
        idxf[wid] = (float)idx;
        atomicAdd(&hist[idx], 1u);
        // decode d_min from the monotone key bits
        uint32_t u = (uint32_t)(key >> 32);
        uint32_t fb = (u & 0x80000000u) ? (u ^ 0x80000000u) : ~u;
        sdv[wvb] = __uint_as_float(fb);
    }
    __syncthreads();
    if (threadIdx.x == 0)
        partials[blockIdx.x] = (sdv[0] + sdv[1]) + (sdv[2] + sdv[3]);
}

// ---------------- finalize: vq_loss from partials + perplexity from hist ----------------
__global__ void finalize_kernel(const float* __restrict__ partials,
                                const unsigned int* __restrict__ hist,
                                float* __restrict__ out_loss,
                                float* __restrict__ out_perp,
                                int NB, int N, int K)
{
    int tid = threadIdx.x;
    double ls = 0.0;
    for (int i = tid; i < NB; i += 1024) ls += (double)partials[i];
    float ent = 0.0f;
    if (tid < K) {
        float p = (float)hist[tid] / (float)N;
        ent = p * logf(p + 1e-10f);
    }
    #pragma unroll
    for (int o = 32; o >= 1; o >>= 1) {
        ls  += __shfl_xor(ls,  o, 64);
        ent += __shfl_xor(ent, o, 64);
    }
    __shared__ double sl[16];
    __shared__ float  se[16];
    int w = tid >> 6, lane = tid & 63;
    if (lane == 0) { sl[w] = ls; se[w] = ent; }
    __syncthreads();
    if (tid == 0) {
        double L = 0.0; float En = 0.0f;
        for (int i = 0; i < 16; ++i) { L += sl[i]; En += se[i]; }
        *out_loss = (float)(0.25 * L / ((double)N * (double)D));
        *out_perp = expf(-En);
    }
}

extern "C" void kernel_launch(void* const* d_in, const int* in_sizes, int n_in,
                              void* d_out, int out_size, void* d_ws, size_t ws_size,
                              hipStream_t stream)
{
    const float* X = (const float*)d_in[0];
    const float* E = (const float*)d_in[1];
    const int N = in_sizes[0] / D;   // 65536
    const int K = in_sizes[1] / D;   // 1024
    float* out = (float*)d_out;

    const size_t O1 = 1;                          // quantized_st  [N*D]
    const size_t O2 = O1 + (size_t)N * D;         // perplexity    [1]
    const size_t O3 = O2 + 1;                     // encodings     [N*K]
    const size_t O4 = O3 + (size_t)N * K;         // distances     [N*K]
    const size_t O5 = O4 + (size_t)N * K;         // indices       [N]

    char* ws = (char*)d_ws;
    size_t off = 0;
    auto alloc = [&](size_t bytes) -> void* {
        void* p = ws + off;
        off += (bytes + 255) & ~(size_t)255;
        return p;
    };
    float* xn = (float*)alloc((size_t)N * 4);
    float* en = (float*)alloc((size_t)K * 4);
    unsigned long long* keys = (unsigned long long*)alloc((size_t)N * 8);
    unsigned int* hist = (unsigned int*)alloc((size_t)K * 4);
    float* partials = (float*)alloc((size_t)(N / 4) * 4);
    unsigned short* Xh = (unsigned short*)alloc((size_t)N * D * 2);
    unsigned short* Xl = (unsigned short*)alloc((size_t)N * D * 2);
    unsigned short* Eh = (unsigned short*)alloc((size_t)K * D * 2);
    unsigned short* El = (unsigned short*)alloc((size_t)K * D * 2);

    int prep_blocks = (N + K + 3) / 4;
    prep_kernel<<<prep_blocks, 256, 0, stream>>>(X, E, xn, en, Xh, Xl, Eh, El,
                                                 keys, hist, N, K);

    dim3 g(K / BN, N / BM);
    dist_mfma<<<g, 256, 0, stream>>>(Xh, Xl, Eh, El, xn, en,
                                     out + O4, keys, N, K);

    row_out<<<N / 4, 256, 0, stream>>>(E, keys, out + O1, out + O3,
                                       out + O5, hist, partials, N, K);

    finalize_kernel<<<1, 1024, 0, stream>>>(partials, hist, out, out + O2,
                                            N / 4, N, K);
}

// Round 10
// 221.843 us; speedup vs baseline: 4.3228x; 1.0617x over previous
//
#include <hip/hip_runtime.h>
#include <hip/hip_fp16.h>
#include <stdint.h>

#define D 256
#define BM 128
#define BN 128
#define EPS 68   // epilogue LDS row stride in floats

#define GLOBAL_AS __attribute__((address_space(1)))
#define LDS_AS    __attribute__((address_space(3)))

typedef _Float16 f16x8 __attribute__((ext_vector_type(8)));
typedef float f32x4 __attribute__((ext_vector_type(4)));

__device__ __forceinline__ void gload16(const unsigned short* g, unsigned short* l) {
    __builtin_amdgcn_global_load_lds((const GLOBAL_AS void*)g, (LDS_AS void*)l, 16, 0, 0);
}

// ---------------- prep: norms (f64 sum -> f32 store) + fp16 hi/scaled-lo split (PANEL-SLAB) ----------------
// slab layout: ushort off = ((panel*8 + chunk)*128 + row)*32 + rot_slot*8 + half*4
// rot_slot = (slot + (row>>1)) & 3  -> bank-conflict-free column reads in dist_mfma
__global__ void prep_kernel(const float* __restrict__ X, const float* __restrict__ E,
                            float* __restrict__ xn, float* __restrict__ en,
                            unsigned short* __restrict__ Xh, unsigned short* __restrict__ Xl,
                            unsigned short* __restrict__ Eh, unsigned short* __restrict__ El,
                            unsigned long long* __restrict__ keys,
                            unsigned int* __restrict__ hist, int N, int K)
{
    int gid  = blockIdx.x * blockDim.x + threadIdx.x;
    int wid  = gid >> 6;
    int lane = threadIdx.x & 63;
    if (wid < N + K) {
        bool isX = wid < N;
        int r = isX ? wid : wid - N;
        const float* src = isX ? (X + (size_t)r * D) : (E + (size_t)r * D);
        float4 v = *(const float4*)(src + lane * 4);
        double s = (double)v.x*v.x + (double)v.y*v.y + (double)v.z*v.z + (double)v.w*v.w;
        #pragma unroll
        for (int o = 32; o >= 1; o >>= 1) s += __shfl_xor(s, o, 64);

        ushort4 h4, l4;
        {
            __half h;
            h = __float2half_rn(v.x); h4.x = __half_as_ushort(h);
            l4.x = __half_as_ushort(__float2half_rn((v.x - __half2float(h)) * 4096.0f));
            h = __float2half_rn(v.y); h4.y = __half_as_ushort(h);
            l4.y = __half_as_ushort(__float2half_rn((v.y - __half2float(h)) * 4096.0f));
            h = __float2half_rn(v.z); h4.z = __half_as_ushort(h);
            l4.z = __half_as_ushort(__float2half_rn((v.z - __half2float(h)) * 4096.0f));
            h = __float2half_rn(v.w); h4.w = __half_as_ushort(h);
            l4.w = __half_as_ushort(__float2half_rn((v.w - __half2float(h)) * 4096.0f));
        }
        int p = r >> 7, ri = r & 127;
        int c = lane >> 3, g = lane & 7;
        int slot = g >> 1, hf = g & 1;
        int slot_r = (slot + (ri >> 1)) & 3;
        size_t off = ((size_t)(p * 8 + c) * 128 + ri) * 32 + slot_r * 8 + hf * 4;
        if (isX) {
            *(ushort4*)(Xh + off) = h4; *(ushort4*)(Xl + off) = l4;
            if (lane == 0) xn[r] = (float)s;
        } else {
            *(ushort4*)(Eh + off) = h4; *(ushort4*)(El + off) = l4;
            if (lane == 0) en[r] = (float)s;
        }
    }
    int stride = gridDim.x * blockDim.x;
    for (int i = gid; i < N; i += stride) keys[i] = 0xFFFFFFFFFFFFFFFFull;
    for (int i = gid; i < K; i += stride) hist[i] = 0u;
}

// ---------------- dist via fp16x2-split MFMA, gload_lds double-buffer, 1 barrier/chunk ----------------
__global__ __launch_bounds__(256, 2) void dist_mfma(
    const unsigned short* __restrict__ Xh, const unsigned short* __restrict__ Xl,
    const unsigned short* __restrict__ Eh, const unsigned short* __restrict__ El,
    const float* __restrict__ xn, const float* __restrict__ en,
    float* __restrict__ dist, unsigned long long* __restrict__ keys,
    int N, int K)
{
    __shared__ alignas(16) unsigned short smem[2 * 4 * 4096];   // 64 KB

    const int tid  = threadIdx.x;
    const int lane = tid & 63;
    const int wv   = tid >> 6;
    const int wrow = (wv & 1) * 64;
    const int wcol = (wv >> 1) * 64;

    // XCD-aware swizzle (gridDim.x == 8)
    const int flat = blockIdx.y * gridDim.x + blockIdx.x;
    const int nf   = (flat & 7) * ((int)(gridDim.x * gridDim.y) >> 3) + (flat >> 3);
    const int bx   = nf & 7;
    const int by   = nf >> 3;
    const int row0 = by * BM;
    const int col0 = bx * BN;

    const unsigned short* gA_h = Xh + (size_t)by * 32768;
    const unsigned short* gA_l = Xl + (size_t)by * 32768;
    const unsigned short* gB_h = Eh + (size_t)bx * 32768;
    const unsigned short* gB_l = El + (size_t)bx * 32768;

    f32x4 acc[4][4];   // hh
    f32x4 acr[4][4];   // cross (scaled by 2^12)
    #pragma unroll
    for (int i = 0; i < 4; ++i)
        #pragma unroll
        for (int j = 0; j < 4; ++j) { acc[i][j] = {0.f,0.f,0.f,0.f}; acr[i][j] = {0.f,0.f,0.f,0.f}; }

    const int toff = tid * 8;

    #define STAGE(c_, b_)                                                           \
    {                                                                               \
        const int co = (c_) * 4096;                                                 \
        unsigned short* lb = smem + (b_) * 16384;                                   \
        _Pragma("unroll")                                                           \
        for (int t = 0; t < 2; ++t) {                                               \
            gload16(gA_h + co + t*2048 + toff, lb +         t*2048 + toff);         \
            gload16(gA_l + co + t*2048 + toff, lb +  4096 + t*2048 + toff);         \
            gload16(gB_h + co + t*2048 + toff, lb +  8192 + t*2048 + toff);         \
            gload16(gB_l + co + t*2048 + toff, lb + 12288 + t*2048 + toff);         \
        }                                                                           \
    }

    const int fr = lane & 15;
    const int kq = lane >> 4;
    const int q  = kq;

    // loop-invariant swizzled LDS offsets (ushort units)
    int offA[4], offB[4];
    #pragma unroll
    for (int i = 0; i < 4; ++i) {
        int rowA = wrow + i*16 + fr;
        offA[i] = rowA * 32 + ((kq + (rowA >> 1)) & 3) * 8;
        int rowB = wcol + i*16 + fr;
        offB[i] = rowB * 32 + ((kq + (rowB >> 1)) & 3) * 8;
    }

    STAGE(0, 0);

    for (int c = 0; c < 8; ++c) {
        const int b = c & 1;
        // wait own DMA for chunk c (free in steady state: a full chunk of compute elapsed)
        asm volatile("s_waitcnt vmcnt(0)" ::: "memory");
        __builtin_amdgcn_s_barrier();           // all waves' chunk-c data landed;
        __builtin_amdgcn_sched_barrier(0);      // and all waves done reading buf b^1 (chunk c-1)
        if (c < 7) STAGE(c + 1, b ^ 1);

        const unsigned short* buf = smem + b * 16384;
        f16x8 ah[4], bh[4], al[4], bl[4];
        #pragma unroll
        for (int i = 0; i < 4; ++i)
            ah[i] = *(const f16x8*)&buf[offA[i]];
        #pragma unroll
        for (int j = 0; j < 4; ++j)
            bh[j] = *(const f16x8*)&buf[8192 + offB[j]];
        __builtin_amdgcn_s_setprio(1);
        #pragma unroll
        for (int i = 0; i < 4; ++i)
            #pragma unroll
            for (int j = 0; j < 4; ++j)
                acc[i][j] = __builtin_amdgcn_mfma_f32_16x16x32_f16(ah[i], bh[j], acc[i][j], 0, 0, 0);
        #pragma unroll
        for (int j = 0; j < 4; ++j)
            bl[j] = *(const f16x8*)&buf[12288 + offB[j]];
        #pragma unroll
        for (int i = 0; i < 4; ++i)
            #pragma unroll
            for (int j = 0; j < 4; ++j)
                acr[i][j] = __builtin_amdgcn_mfma_f32_16x16x32_f16(ah[i], bl[j], acr[i][j], 0, 0, 0);
        #pragma unroll
        for (int i = 0; i < 4; ++i)
            al[i] = *(const f16x8*)&buf[4096 + offA[i]];
        #pragma unroll
        for (int i = 0; i < 4; ++i)
            #pragma unroll
            for (int j = 0; j < 4; ++j)
                acr[i][j] = __builtin_amdgcn_mfma_f32_16x16x32_f16(al[i], bh[j], acr[i][j], 0, 0, 0);
        __builtin_amdgcn_s_setprio(0);
    }

    // single barrier before epilogue: arenas overlap the staging buffers
    asm volatile("s_waitcnt lgkmcnt(0)" ::: "memory");
    __builtin_amdgcn_s_barrier();
    __builtin_amdgcn_sched_barrier(0);

    // ---- epilogue, all f32 ----
    float ecv[4];
    #pragma unroll
    for (int j = 0; j < 4; ++j) ecv[j] = en[col0 + wcol + j*16 + fr];

    char* arena = (char*)smem + wv * 16384;

    // Phase A: per-thread keys -> LDS table -> per-lane row reduce -> atomicMin
    {
        unsigned long long* kbuf = (unsigned long long*)arena;   // [64][17] u64 = 8704B
        #pragma unroll
        for (int i = 0; i < 4; ++i) {
            #pragma unroll
            for (int r = 0; r < 4; ++r) {
                const int lr = i*16 + q*4 + r;
                unsigned long long bk = 0xFFFFFFFFFFFFFFFFull;
                #pragma unroll
                for (int j = 0; j < 4; ++j) {
                    float dotf = fmaf(acr[i][j][r], 0.000244140625f, acc[i][j][r]);
                    float m    = fmaf(-2.0f, dotf, ecv[j]);
                    uint32_t u = __float_as_uint(m);
                    u ^= ((uint32_t)((int32_t)u >> 31)) | 0x80000000u;
                    unsigned long long kk = ((unsigned long long)u << 32)
                                          | (unsigned)(col0 + wcol + j*16 + fr);
                    if (kk < bk) bk = kk;
                }
                kbuf[lr * 17 + fr] = bk;
            }
        }
        asm volatile("s_waitcnt lgkmcnt(0)" ::: "memory");
        unsigned long long best = 0xFFFFFFFFFFFFFFFFull;
        #pragma unroll
        for (int s = 0; s < 16; ++s) {
            unsigned long long v = kbuf[lane * 17 + s];
            if (v < best) best = v;
        }
        // rebase key to full distance dv = xn + m so keys carry d_min for the loss
        {
            uint32_t u = (uint32_t)(best >> 32);
            uint32_t fb = (u & 0x80000000u) ? (u ^ 0x80000000u) : ~u;
            float m = __uint_as_float(fb);
            float dv = xn[row0 + wrow + lane] + m;
            uint32_t du = __float_as_uint(dv);
            du ^= ((uint32_t)((int32_t)du >> 31)) | 0x80000000u;
            best = ((unsigned long long)du << 32) | (best & 0xFFFFFFFFull);
        }
        atomicMin(&keys[row0 + wrow + lane], best);
        asm volatile("s_waitcnt lgkmcnt(0)" ::: "memory");
    }

    // Phase B: dist values via LDS-staged full-line nontemporal float4 stores
    {
        float xr32[4][4];
        #pragma unroll
        for (int i = 0; i < 4; ++i)
            #pragma unroll
            for (int r = 0; r < 4; ++r)
                xr32[i][r] = xn[row0 + wrow + i*16 + q*4 + r];

        float* ebuf = (float*)arena;
        #pragma unroll
        for (int h = 0; h < 2; ++h) {
            #pragma unroll
            for (int i2 = 0; i2 < 2; ++i2) {
                const int i = h * 2 + i2;
                #pragma unroll
                for (int r = 0; r < 4; ++r) {
                    #pragma unroll
                    for (int j = 0; j < 4; ++j) {
                        float dotf = fmaf(acr[i][j][r], 0.000244140625f, acc[i][j][r]);
                        float dv   = fmaf(-2.0f, dotf, xr32[i][r] + ecv[j]);
                        ebuf[(i2*16 + q*4 + r) * EPS + j*16 + fr] = dv;
                    }
                }
            }
            asm volatile("s_waitcnt lgkmcnt(0)" ::: "memory");
            #pragma unroll
            for (int s = 0; s < 8; ++s) {
                const int rl = s*4 + q;
                f32x4 v = *(const f32x4*)&ebuf[rl * EPS + fr * 4];
                const int grow = row0 + wrow + h*32 + rl;
                __builtin_nontemporal_store(v, (f32x4*)&dist[(size_t)grow * K + col0 + wcol + fr*4]);
            }
            asm volatile("s_waitcnt lgkmcnt(0)" ::: "memory");
        }
    }
    #undef STAGE
}

// ---------------- per-row outputs: gather quantized, one-hot, idx, hist, loss partial ----------------
__global__ void row_out(const float* __restrict__ E,
                        const unsigned long long* __restrict__ keys,
                        float* __restrict__ quant, float* __restrict__ enc,
                        float* __restrict__ idxf, unsigned int* __restrict__ hist,
                        float* __restrict__ partials, int N, int K)
{
    __shared__ float sdv[4];
    int wid  = (blockIdx.x * blockDim.x + threadIdx.x) >> 6;
    int wvb  = (threadIdx.x) >> 6;      // wave within block 0..3
    int lane = threadIdx.x & 63;
    unsigned long long key = keys[wid];
    int idx = (int)(unsigned)(key & 0xFFFFFFFFull);

    f32x4 q4 = *(const f32x4*)(E + (size_t)idx * D + lane*4);
    __builtin_nontemporal_store(q4, (f32x4*)(quant + (size_t)wid * D + lane*4));

    #pragma unroll
    for (int c = 0; c < 4; ++c) {
        int col = c * 256 + lane * 4;
        f32x4 v;
        v[0] = (col + 0 == idx) ? 1.0f : 0.0f;
        v[1] = (col + 1 == idx) ? 1.0f : 0.0f;
        v[2] = (col + 2 == idx) ? 1.0f : 0.0f;
        v[3] = (col + 3 == idx) ? 1.0f : 0.0f;
        __builtin_nontemporal_store(v, (f32x4*)(enc + (size_t)wid * K + col));
    }
    if (lane == 0) {
        idxf[wid] = (float)idx;
        atomicAdd(&hist[idx], 1u);
        // decode d_min from the monotone key bits
        uint32_t u = (uint32_t)(key >> 32);
        uint32_t fb = (u & 0x80000000u) ? (u ^ 0x80000000u) : ~u;
        sdv[wvb] = __uint_as_float(fb);
    }
    __syncthreads();
    if (threadIdx.x == 0)
        partials[blockIdx.x] = (sdv[0] + sdv[1]) + (sdv[2] + sdv[3]);
}

// ---------------- finalize: vq_loss from partials + perplexity from hist ----------------
__global__ void finalize_kernel(const float* __restrict__ partials,
                                const unsigned int* __restrict__ hist,
                                float* __restrict__ out_loss,
                                float* __restrict__ out_perp,
                                int NB, int N, int K)
{
    int tid = threadIdx.x;
    double ls = 0.0;
    for (int i = tid; i < NB; i += 1024) ls += (double)partials[i];
    float ent = 0.0f;
    if (tid < K) {
        float p = (float)hist[tid] / (float)N;
        ent = p * logf(p + 1e-10f);
    }
    #pragma unroll
    for (int o = 32; o >= 1; o >>= 1) {
        ls  += __shfl_xor(ls,  o, 64);
        ent += __shfl_xor(ent, o, 64);
    }
    __shared__ double sl[16];
    __shared__ float  se[16];
    int w = tid >> 6, lane = tid & 63;
    if (lane == 0) { sl[w] = ls; se[w] = ent; }
    __syncthreads();
    if (tid == 0) {
        double L = 0.0; float En = 0.0f;
        for (int i = 0; i < 16; ++i) { L += sl[i]; En += se[i]; }
        *out_loss = (float)(0.25 * L / ((double)N * (double)D));
        *out_perp = expf(-En);
    }
}

extern "C" void kernel_launch(void* const* d_in, const int* in_sizes, int n_in,
                              void* d_out, int out_size, void* d_ws, size_t ws_size,
                              hipStream_t stream)
{
    const float* X = (const float*)d_in[0];
    const float* E = (const float*)d_in[1];
    const int N = in_sizes[0] / D;   // 65536
    const int K = in_sizes[1] / D;   // 1024
    float* out = (float*)d_out;

    const size_t O1 = 1;                          // quantized_st  [N*D]
    const size_t O2 = O1 + (size_t)N * D;         // perplexity    [1]
    const size_t O3 = O2 + 1;                     // encodings     [N*K]
    const size_t O4 = O3 + (size_t)N * K;         // distances     [N*K]
    const size_t O5 = O4 + (size_t)N * K;         // indices       [N]

    char* ws = (char*)d_ws;
    size_t off = 0;
    auto alloc = [&](size_t bytes) -> void* {
        void* p = ws + off;
        off += (bytes + 255) & ~(size_t)255;
        return p;
    };
    float* xn = (float*)alloc((size_t)N * 4);
    float* en = (float*)alloc((size_t)K * 4);
    unsigned long long* keys = (unsigned long long*)alloc((size_t)N * 8);
    unsigned int* hist = (unsigned int*)alloc((size_t)K * 4);
    float* partials = (float*)alloc((size_t)(N / 4) * 4);
    unsigned short* Xh = (unsigned short*)alloc((size_t)N * D * 2);
    unsigned short* Xl = (unsigned short*)alloc((size_t)N * D * 2);
    unsigned short* Eh = (unsigned short*)alloc((size_t)K * D * 2);
    unsigned short* El = (unsigned short*)alloc((size_t)K * D * 2);

    int prep_blocks = (N + K + 3) / 4;
    prep_kernel<<<prep_blocks, 256, 0, stream>>>(X, E, xn, en, Xh, Xl, Eh, El,
                                                 keys, hist, N, K);

    dim3 g(K / BN, N / BM);
    dist_mfma<<<g, 256, 0, stream>>>(Xh, Xl, Eh, El, xn, en,
                                     out + O4, keys, N, K);

    row_out<<<N / 4, 256, 0, stream>>>(E, keys, out + O1, out + O3,
                                       out + O5, hist, partials, N, K);

    finalize_kernel<<<1, 1024, 0, stream>>>(partials, hist, out, out + O2,
                                            N / 4, N, K);
}